// Round 3
// baseline (549.384 us; speedup 1.0000x reference)
//
#include <hip/hip_runtime.h>
#include <hip/hip_bf16.h>
#include <cstdint>

// Problem constants
#define Bb  8
#define Tt  2048
#define Cc  256
#define FDd 256
#define Kk  128
#define Vv  256
#define BT  (Bb * Tt)

#define INV_SQRT_K 0.08838834764831845f  // 1/sqrt(128)

typedef __bf16 bf16x8 __attribute__((ext_vector_type(8)));
typedef __bf16 bf16x4 __attribute__((ext_vector_type(4)));
typedef float  f32x4  __attribute__((ext_vector_type(4)));

// ---------------------------------------------------------------------------
// prep: out[:, :256] = inp (fp32 copy) + bf16 conversions of inp and feature.
//   grid 4096, block 256. One thread = one float4 of inp + one of feat.
// ---------------------------------------------------------------------------
__global__ __launch_bounds__(256) void prep_kernel(
    const float4* __restrict__ inp4, const float4* __restrict__ feat4,
    float4* __restrict__ out4, bf16x4* __restrict__ inpB4,
    bf16x4* __restrict__ featB4)
{
  const int g = blockIdx.x * 256 + threadIdx.x;   // 0 .. BT*64
  const int row = g >> 6, c = g & 63;
  const float4 x = inp4[g];
  out4[(size_t)row * 128 + c] = x;
  bf16x4 xb; xb[0] = (__bf16)x.x; xb[1] = (__bf16)x.y; xb[2] = (__bf16)x.z; xb[3] = (__bf16)x.w;
  inpB4[g] = xb;
  const float4 f = feat4[g];
  bf16x4 fb; fb[0] = (__bf16)f.x; fb[1] = (__bf16)f.y; fb[2] = (__bf16)f.z; fb[3] = (__bf16)f.w;
  featB4[g] = fb;
}

// ---------------------------------------------------------------------------
// wprep: transpose + bf16-convert weights. Wqt[n][k]=Wq[k][n] etc.
//   grid 640, block 256 (163840 elements total).
// ---------------------------------------------------------------------------
__global__ __launch_bounds__(256) void wprep_kernel(
    const float* __restrict__ Wq, const float* __restrict__ Wk,
    const float* __restrict__ Wv, __bf16* __restrict__ Wqt,
    __bf16* __restrict__ Wkt, __bf16* __restrict__ Wvt)
{
  const int g = blockIdx.x * 256 + threadIdx.x;
  if (g < 65536) {                       // Wq: 512x128 -> Wqt 128x512
    const int n = g >> 9, k = g & 511;
    Wqt[g] = (__bf16)Wq[k * 128 + n];
  } else if (g < 98304) {                // Wk: 256x128 -> Wkt 128x256
    const int h = g - 65536;
    const int n = h >> 8, k = h & 255;
    Wkt[h] = (__bf16)Wk[k * 128 + n];
  } else {                               // Wv: 256x256 -> Wvt 256x256
    const int h = g - 98304;
    const int n = h >> 8, k = h & 255;
    Wvt[h] = (__bf16)Wv[k * 256 + n];
  }
}

// ---------------------------------------------------------------------------
// qkv via MFMA. grid (BT/64, 4), block 256 (4 waves x 16 rows).
//   panel 0: Q (N=128, K=512: inpB then featB), scale+bias in epilogue
//   panel 1: K (N=128, K=256)
//   panel 2: V cols [0,128), panel 3: V cols [128,256) -> vT[b][vcol][t]
// A-frag: A[m=cl][kk=quad*8+j] from row-major activations (16B loads).
// B-frag: B[kk][n=cl] from transposed weights (16B loads, L2-resident).
// ---------------------------------------------------------------------------
__global__ __launch_bounds__(256) void qkv_mfma_kernel(
    const __bf16* __restrict__ inpB, const __bf16* __restrict__ featB,
    const __bf16* __restrict__ Wqt, const __bf16* __restrict__ Wkt,
    const __bf16* __restrict__ Wvt,
    const float* __restrict__ bq, const float* __restrict__ bk,
    const float* __restrict__ bv,
    __bf16* __restrict__ qb, __bf16* __restrict__ kb, __bf16* __restrict__ vT)
{
  const int panel = blockIdx.y;
  const int lane = threadIdx.x & 63, wave = threadIdx.x >> 6;
  const int cl = lane & 15, quad = lane >> 4;
  const int row0 = blockIdx.x * 64 + wave * 16;

  const __bf16* Wt; const float* bias; int Kd;
  if (panel == 0)      { Wt = Wqt; bias = bq; Kd = 512; }
  else if (panel == 1) { Wt = Wkt; bias = bk; Kd = 256; }
  else                 { Wt = Wvt + (size_t)(panel - 2) * 128 * 256;
                         bias = bv + (panel - 2) * 128; Kd = 256; }

  f32x4 acc[8];
#pragma unroll
  for (int nt = 0; nt < 8; ++nt) acc[nt] = (f32x4){0.f, 0.f, 0.f, 0.f};

  const __bf16* arow_i = inpB + (size_t)(row0 + cl) * 256 + quad * 8;
  const __bf16* arow_f = featB + (size_t)(row0 + cl) * 256 + quad * 8;
  const __bf16* wrow   = Wt + (size_t)cl * Kd + quad * 8;

#pragma unroll 2
  for (int k0 = 0; k0 < 256; k0 += 32) {
    const bf16x8 af = *(const bf16x8*)(arow_i + k0);
#pragma unroll
    for (int nt = 0; nt < 8; ++nt) {
      const bf16x8 bfr = *(const bf16x8*)(wrow + (size_t)nt * 16 * Kd + k0);
      acc[nt] = __builtin_amdgcn_mfma_f32_16x16x32_bf16(af, bfr, acc[nt], 0, 0, 0);
    }
  }
  if (Kd == 512) {  // Q second half from feature
#pragma unroll 2
    for (int k0 = 0; k0 < 256; k0 += 32) {
      const bf16x8 af = *(const bf16x8*)(arow_f + k0);
#pragma unroll
      for (int nt = 0; nt < 8; ++nt) {
        const bf16x8 bfr = *(const bf16x8*)(wrow + (size_t)nt * 16 * Kd + 256 + k0);
        acc[nt] = __builtin_amdgcn_mfma_f32_16x16x32_bf16(af, bfr, acc[nt], 0, 0, 0);
      }
    }
  }

  if (panel < 2) {
    __bf16* dst = (panel == 0) ? qb : kb;
    const float scale = (panel == 0) ? INV_SQRT_K : 1.0f;
#pragma unroll
    for (int nt = 0; nt < 8; ++nt) {
      const float bs = bias[nt * 16 + cl];
#pragma unroll
      for (int r = 0; r < 4; ++r)
        dst[(size_t)(row0 + quad * 4 + r) * Kk + nt * 16 + cl] =
            (__bf16)((acc[nt][r] + bs) * scale);
    }
  } else {
    const int b = row0 >> 11, t0 = (row0 & (Tt - 1)) + quad * 4;
#pragma unroll
    for (int nt = 0; nt < 8; ++nt) {
      const float bs = bias[nt * 16 + cl];
      bf16x4 v4;
#pragma unroll
      for (int r = 0; r < 4; ++r) v4[r] = (__bf16)(acc[nt][r] + bs);
      *(bf16x4*)(vT + (size_t)(b * Vv + (panel - 2) * 128 + nt * 16 + cl) * Tt + t0) = v4;
    }
  }
}

// ---------------------------------------------------------------------------
// colstats partials: partialD[b][jc][i] = sum_{j in chunk jc, j>=i} exp(s[j,i])
//   grid (32, 8, 8), block 256 (4 waves x 16 cols). <=16 MFMA steps per wave.
// ---------------------------------------------------------------------------
__global__ __launch_bounds__(256) void colstats_part_kernel(
    const __bf16* __restrict__ qb, const __bf16* __restrict__ kb,
    float* __restrict__ partialD)
{
  const int b = blockIdx.z, jc = blockIdx.y;
  const int lane = threadIdx.x & 63, wave = threadIdx.x >> 6;
  const int cl = lane & 15, quad = lane >> 4;
  const int iw = blockIdx.x * 64 + wave * 16;
  const int col = iw + cl;
  const size_t rowbase = (size_t)b * Tt;

  float d = 0.f;
  const int jlo = max(jc * 256, iw);
  const int jhi = jc * 256 + 256;
  if (jlo < jhi) {
    bf16x8 bf[4];   // B-frag: kb[col][kk]
    const __bf16* krow = kb + (rowbase + col) * Kk + quad * 8;
#pragma unroll
    for (int s = 0; s < 4; ++s) bf[s] = *(const bf16x8*)(krow + s * 32);

    for (int j0 = jlo; j0 < jhi; j0 += 16) {
      const __bf16* qrow = qb + (rowbase + j0 + cl) * Kk + quad * 8;
      f32x4 c = {0.f, 0.f, 0.f, 0.f};
#pragma unroll
      for (int s = 0; s < 4; ++s) {
        const bf16x8 af = *(const bf16x8*)(qrow + s * 32);
        c = __builtin_amdgcn_mfma_f32_16x16x32_bf16(af, bf[s], c, 0, 0, 0);
      }
#pragma unroll
      for (int r = 0; r < 4; ++r) {
        const int j = j0 + quad * 4 + r;
        d += (j >= col) ? __expf(c[r]) : 0.f;
      }
    }
  }
  d += __shfl_xor(d, 16);
  d += __shfl_xor(d, 32);
  if (quad == 0) partialD[(size_t)(b * 8 + jc) * Tt + col] = d;
}

// ---------------------------------------------------------------------------
// dreduce: recipD[b][i] = 1 / sum_jc partialD[b][jc][i].
//   grid 64 blocks x 256 threads = 16384 = B*T.  (Round-2 bug: launched 16.)
// ---------------------------------------------------------------------------
__global__ __launch_bounds__(256) void dreduce_kernel(
    const float* __restrict__ partialD, float* __restrict__ recipD)
{
  const int g = blockIdx.x * 256 + threadIdx.x;  // 0..16383
  const int b = g >> 11, i = g & (Tt - 1);
  float s = 0.f;
#pragma unroll
  for (int jc = 0; jc < 8; ++jc) s += partialD[(size_t)(b * 8 + jc) * Tt + i];
  recipD[g] = 1.0f / s;
}

// ---------------------------------------------------------------------------
// attn: out[:, :, 256:512] = P @ v, P[j,i] = exp(s[j,i])*recipD[i], i<=j.
//   grid (32 jt reversed, 4 vsplit, 8 b), block 256 (4 waves x 16 j-rows).
//   Each block owns 64 j-rows x 64 v-cols -> direct stores, no atomics.
//   S' = K.Q^T recomputed per vsplit (C/D rows = i so recipD is float4/reg);
//   LDS round-trip to A-operand layout (wave-private, no barrier).
// ---------------------------------------------------------------------------
__global__ __launch_bounds__(256) void attn_part_kernel(
    const __bf16* __restrict__ qb, const __bf16* __restrict__ kb,
    const __bf16* __restrict__ vT, const float* __restrict__ recipD,
    float* __restrict__ out)
{
  __shared__ __bf16 plds[4][16 * 40];
  const int b = blockIdx.z, vs = blockIdx.y;
  const int jt = 31 - blockIdx.x;           // longest blocks dispatch first
  const int lane = threadIdx.x & 63, wave = threadIdx.x >> 6;
  const int cl = lane & 15, quad = lane >> 4;
  const int jw = jt * 64 + wave * 16;
  const size_t rowbase = (size_t)b * Tt;

  bf16x8 qf[4];   // B-frag: qb[jw+cl][kk], fixed all kernel
  {
    const __bf16* qrow = qb + (rowbase + jw + cl) * Kk + quad * 8;
#pragma unroll
    for (int s = 0; s < 4; ++s) qf[s] = *(const bf16x8*)(qrow + s * 32);
  }

  f32x4 acc[4];
#pragma unroll
  for (int nt = 0; nt < 4; ++nt) acc[nt] = (f32x4){0.f, 0.f, 0.f, 0.f};

  __bf16* myp = &plds[wave][0];
  const float* rD = recipD + rowbase;
  const __bf16* vbase = vT + ((size_t)b * Vv + vs * 64) * Tt;

  const int nsteps = (jw >> 5) + 1;
  for (int st = 0; st < nsteps; ++st) {
    const int i0 = st * 32;
#pragma unroll
    for (int t = 0; t < 2; ++t) {
      const int it = i0 + t * 16;
      const __bf16* krow = kb + (rowbase + it + cl) * Kk + quad * 8;  // A: m=i
      f32x4 c = {0.f, 0.f, 0.f, 0.f};
#pragma unroll
      for (int s = 0; s < 4; ++s) {
        const bf16x8 af = *(const bf16x8*)(krow + s * 32);
        c = __builtin_amdgcn_mfma_f32_16x16x32_bf16(af, qf[s], c, 0, 0, 0);
      }
      const f32x4 rd4 = *(const f32x4*)(rD + it + quad * 4);
      bf16x4 pv;
#pragma unroll
      for (int r = 0; r < 4; ++r) {
        const int i = it + quad * 4 + r;
        const float p = (i <= jw + cl) ? __expf(c[r]) * rd4[r] : 0.f;
        pv[r] = (__bf16)p;
      }
      *(bf16x4*)(myp + cl * 40 + t * 16 + quad * 4) = pv;
    }
    const bf16x8 pf = *(const bf16x8*)(myp + cl * 40 + quad * 8);  // A: m=j, k=i
#pragma unroll
    for (int nt = 0; nt < 4; ++nt) {
      const __bf16* vrow = vbase + (size_t)(nt * 16 + cl) * Tt + i0 + quad * 8;
      const bf16x8 vf = *(const bf16x8*)(vrow);
      acc[nt] = __builtin_amdgcn_mfma_f32_16x16x32_bf16(pf, vf, acc[nt], 0, 0, 0);
    }
  }

  float* orow = out + (rowbase + jw) * (size_t)(Cc + Vv) + Cc + vs * 64;
#pragma unroll
  for (int nt = 0; nt < 4; ++nt)
#pragma unroll
    for (int r = 0; r < 4; ++r)
      orow[(size_t)(quad * 4 + r) * (Cc + Vv) + nt * 16 + cl] = acc[nt][r];
}

// ---------------------------------------------------------------------------
extern "C" void kernel_launch(void* const* d_in, const int* in_sizes, int n_in,
                              void* d_out, int out_size, void* d_ws, size_t ws_size,
                              hipStream_t stream) {
  const float* inp  = (const float*)d_in[0];
  const float* feat = (const float*)d_in[1];
  const float* Wq   = (const float*)d_in[2];
  const float* bq   = (const float*)d_in[3];
  const float* Wk   = (const float*)d_in[4];
  const float* bk   = (const float*)d_in[5];
  const float* Wv   = (const float*)d_in[6];
  const float* bv   = (const float*)d_in[7];
  float* out = (float*)d_out;

  // ws layout (34.5 MB):
  //  inpB 8MB | featB 8MB | qb 4MB | kb 4MB | vT 8MB |
  //  Wqt 128K | Wkt 64K | Wvt 128K | partialD 512K | recipD 64K
  char* ws = (char*)d_ws;
  __bf16* inpB   = (__bf16*)(ws);
  __bf16* featB  = (__bf16*)(ws + (8u << 20));
  __bf16* qb     = (__bf16*)(ws + (16u << 20));
  __bf16* kb     = (__bf16*)(ws + (20u << 20));
  __bf16* vT     = (__bf16*)(ws + (24u << 20));
  __bf16* Wqt    = (__bf16*)(ws + (32u << 20));
  __bf16* Wkt    = (__bf16*)(ws + (32u << 20) + (128u << 10));
  __bf16* Wvt    = (__bf16*)(ws + (32u << 20) + (192u << 10));
  float*  partialD = (float*)(ws + (32u << 20) + (320u << 10));
  float*  recipD   = (float*)(ws + (32u << 20) + (832u << 10));

  prep_kernel<<<dim3(BT * 64 / 256), 256, 0, stream>>>(
      (const float4*)inp, (const float4*)feat, (float4*)out,
      (bf16x4*)inpB, (bf16x4*)featB);
  wprep_kernel<<<dim3(640), 256, 0, stream>>>(Wq, Wk, Wv, Wqt, Wkt, Wvt);
  qkv_mfma_kernel<<<dim3(BT / 64, 4), 256, 0, stream>>>(
      inpB, featB, Wqt, Wkt, Wvt, bq, bk, bv, qb, kb, vT);
  colstats_part_kernel<<<dim3(Tt / 64, 8, Bb), 256, 0, stream>>>(qb, kb, partialD);
  dreduce_kernel<<<dim3(BT / 256), 256, 0, stream>>>(partialD, recipD);
  attn_part_kernel<<<dim3(Tt / 64, 4, Bb), 256, 0, stream>>>(qb, kb, vT, recipD, out);
}

// Round 4
// 246.307 us; speedup vs baseline: 2.2305x; 2.2305x over previous
//
#include <hip/hip_runtime.h>
#include <hip/hip_bf16.h>
#include <cstdint>

// Problem constants
#define Bb  8
#define Tt  2048
#define Cc  256
#define FDd 256
#define Kk  128
#define Vv  256
#define BT  (Bb * Tt)
#define NTRI 136          // 16*17/2 lower-triangular 128x128 blocks per batch

#define INV_SQRT_K 0.08838834764831845f  // 1/sqrt(128)

typedef __bf16 bf16x8 __attribute__((ext_vector_type(8)));
typedef __bf16 bf16x4 __attribute__((ext_vector_type(4)));
typedef float  f32x4  __attribute__((ext_vector_type(4)));

// ---------------------------------------------------------------------------
// prep: out[:, :256] = inp (fp32 copy) + bf16 conversions of inp and feature.
// ---------------------------------------------------------------------------
__global__ __launch_bounds__(256) void prep_kernel(
    const float4* __restrict__ inp4, const float4* __restrict__ feat4,
    float4* __restrict__ out4, bf16x4* __restrict__ inpB4,
    bf16x4* __restrict__ featB4)
{
  const int g = blockIdx.x * 256 + threadIdx.x;   // 0 .. BT*64
  const int row = g >> 6, c = g & 63;
  const float4 x = inp4[g];
  out4[(size_t)row * 128 + c] = x;
  bf16x4 xb; xb[0] = (__bf16)x.x; xb[1] = (__bf16)x.y; xb[2] = (__bf16)x.z; xb[3] = (__bf16)x.w;
  inpB4[g] = xb;
  const float4 f = feat4[g];
  bf16x4 fb; fb[0] = (__bf16)f.x; fb[1] = (__bf16)f.y; fb[2] = (__bf16)f.z; fb[3] = (__bf16)f.w;
  featB4[g] = fb;
}

// ---------------------------------------------------------------------------
// wprep: transpose + bf16-convert weights.
// ---------------------------------------------------------------------------
__global__ __launch_bounds__(256) void wprep_kernel(
    const float* __restrict__ Wq, const float* __restrict__ Wk,
    const float* __restrict__ Wv, __bf16* __restrict__ Wqt,
    __bf16* __restrict__ Wkt, __bf16* __restrict__ Wvt)
{
  const int g = blockIdx.x * 256 + threadIdx.x;
  if (g < 65536) {                       // Wq: 512x128 -> Wqt 128x512
    const int n = g >> 9, k = g & 511;
    Wqt[g] = (__bf16)Wq[k * 128 + n];
  } else if (g < 98304) {                // Wk: 256x128 -> Wkt 128x256
    const int h = g - 65536;
    const int n = h >> 8, k = h & 255;
    Wkt[h] = (__bf16)Wk[k * 128 + n];
  } else {                               // Wv: 256x256 -> Wvt 256x256
    const int h = g - 98304;
    const int n = h >> 8, k = h & 255;
    Wvt[h] = (__bf16)Wv[k * 256 + n];
  }
}

// ---------------------------------------------------------------------------
// qkv via MFMA. grid (BT/64, 4), block 256 (4 waves x 16 rows). (unchanged)
// ---------------------------------------------------------------------------
__global__ __launch_bounds__(256) void qkv_mfma_kernel(
    const __bf16* __restrict__ inpB, const __bf16* __restrict__ featB,
    const __bf16* __restrict__ Wqt, const __bf16* __restrict__ Wkt,
    const __bf16* __restrict__ Wvt,
    const float* __restrict__ bq, const float* __restrict__ bk,
    const float* __restrict__ bv,
    __bf16* __restrict__ qb, __bf16* __restrict__ kb, __bf16* __restrict__ vT)
{
  const int panel = blockIdx.y;
  const int lane = threadIdx.x & 63, wave = threadIdx.x >> 6;
  const int cl = lane & 15, quad = lane >> 4;
  const int row0 = blockIdx.x * 64 + wave * 16;

  const __bf16* Wt; const float* bias; int Kd;
  if (panel == 0)      { Wt = Wqt; bias = bq; Kd = 512; }
  else if (panel == 1) { Wt = Wkt; bias = bk; Kd = 256; }
  else                 { Wt = Wvt + (size_t)(panel - 2) * 128 * 256;
                         bias = bv + (panel - 2) * 128; Kd = 256; }

  f32x4 acc[8];
#pragma unroll
  for (int nt = 0; nt < 8; ++nt) acc[nt] = (f32x4){0.f, 0.f, 0.f, 0.f};

  const __bf16* arow_i = inpB + (size_t)(row0 + cl) * 256 + quad * 8;
  const __bf16* arow_f = featB + (size_t)(row0 + cl) * 256 + quad * 8;
  const __bf16* wrow   = Wt + (size_t)cl * Kd + quad * 8;

#pragma unroll 2
  for (int k0 = 0; k0 < 256; k0 += 32) {
    const bf16x8 af = *(const bf16x8*)(arow_i + k0);
#pragma unroll
    for (int nt = 0; nt < 8; ++nt) {
      const bf16x8 bfr = *(const bf16x8*)(wrow + (size_t)nt * 16 * Kd + k0);
      acc[nt] = __builtin_amdgcn_mfma_f32_16x16x32_bf16(af, bfr, acc[nt], 0, 0, 0);
    }
  }
  if (Kd == 512) {  // Q second half from feature
#pragma unroll 2
    for (int k0 = 0; k0 < 256; k0 += 32) {
      const bf16x8 af = *(const bf16x8*)(arow_f + k0);
#pragma unroll
      for (int nt = 0; nt < 8; ++nt) {
        const bf16x8 bfr = *(const bf16x8*)(wrow + (size_t)nt * 16 * Kd + 256 + k0);
        acc[nt] = __builtin_amdgcn_mfma_f32_16x16x32_bf16(af, bfr, acc[nt], 0, 0, 0);
      }
    }
  }

  if (panel < 2) {
    __bf16* dst = (panel == 0) ? qb : kb;
    const float scale = (panel == 0) ? INV_SQRT_K : 1.0f;
#pragma unroll
    for (int nt = 0; nt < 8; ++nt) {
      const float bs = bias[nt * 16 + cl];
#pragma unroll
      for (int r = 0; r < 4; ++r)
        dst[(size_t)(row0 + quad * 4 + r) * Kk + nt * 16 + cl] =
            (__bf16)((acc[nt][r] + bs) * scale);
    }
  } else {
    const int b = row0 >> 11, t0 = (row0 & (Tt - 1)) + quad * 4;
#pragma unroll
    for (int nt = 0; nt < 8; ++nt) {
      const float bs = bias[nt * 16 + cl];
      bf16x4 v4;
#pragma unroll
      for (int r = 0; r < 4; ++r) v4[r] = (__bf16)(acc[nt][r] + bs);
      *(bf16x4*)(vT + (size_t)(b * Vv + (panel - 2) * 128 + nt * 16 + cl) * Tt + t0) = v4;
    }
  }
}

// ---------------------------------------------------------------------------
// sexp: expS = exp(Q.K^T) for lower-triangular 128x128 blocks (packed slots),
//       + per-block column sums -> partialD[b][jt][i].
//   grid (136, 8), block 256 = 4 waves, wave = 64j x 64i, 64 MFMAs on
//   register-resident frags (all 16B direct loads, qb/kb L2-resident).
//   Slot l = jt*(jt+1)/2 + it, row-major [j_local(128)][i_local(128)].
// ---------------------------------------------------------------------------
__global__ __launch_bounds__(256) void sexp_kernel(
    const __bf16* __restrict__ qb, const __bf16* __restrict__ kb,
    __bf16* __restrict__ expS, float* __restrict__ partialD)
{
  const int b = blockIdx.y, l = blockIdx.x;
  int jt = 0, base = 0;
  while (base + jt + 1 <= l) { base += jt + 1; ++jt; }   // uniform, <=16 iters
  const int it = l - base;

  const int lane = threadIdx.x & 63, wave = threadIdx.x >> 6;
  const int cl = lane & 15, quad = lane >> 4;
  const int j0 = jt * 128 + (wave >> 1) * 64;
  const int i0 = it * 128 + (wave & 1) * 64;
  const size_t rowbase = (size_t)b * Tt;

  bf16x8 af[4][4], bfr[4][4];
  const __bf16* qrow = qb + (rowbase + j0 + cl) * Kk + quad * 8;
  const __bf16* krow = kb + (rowbase + i0 + cl) * Kk + quad * 8;
#pragma unroll
  for (int mt = 0; mt < 4; ++mt)
#pragma unroll
    for (int ks = 0; ks < 4; ++ks) af[mt][ks] = *(const bf16x8*)(qrow + mt * 16 * Kk + ks * 32);
#pragma unroll
  for (int nt = 0; nt < 4; ++nt)
#pragma unroll
    for (int ks = 0; ks < 4; ++ks) bfr[nt][ks] = *(const bf16x8*)(krow + nt * 16 * Kk + ks * 32);

  f32x4 acc[4][4];
#pragma unroll
  for (int mt = 0; mt < 4; ++mt)
#pragma unroll
    for (int nt = 0; nt < 4; ++nt) acc[mt][nt] = (f32x4){0.f, 0.f, 0.f, 0.f};

#pragma unroll
  for (int ks = 0; ks < 4; ++ks)
#pragma unroll
    for (int mt = 0; mt < 4; ++mt)
#pragma unroll
      for (int nt = 0; nt < 4; ++nt)
        acc[mt][nt] = __builtin_amdgcn_mfma_f32_16x16x32_bf16(af[mt][ks], bfr[nt][ks], acc[mt][nt], 0, 0, 0);

  // epilogue: exp, (diag mask), bf16 store to slot, column sums
  __bf16* slot = expS + ((size_t)(b * NTRI + l)) * (128 * 128);
  const bool diag = (it == jt);
  float cs[4] = {0.f, 0.f, 0.f, 0.f};
#pragma unroll
  for (int mt = 0; mt < 4; ++mt) {
    const int jl = (wave >> 1) * 64 + mt * 16 + quad * 4;
#pragma unroll
    for (int nt = 0; nt < 4; ++nt) {
      const int il = (wave & 1) * 64 + nt * 16 + cl;
#pragma unroll
      for (int r = 0; r < 4; ++r) {
        float p = __expf(acc[mt][nt][r]);
        if (diag && (i0 + nt * 16 + cl) > (j0 + mt * 16 + quad * 4 + r)) p = 0.f;
        const __bf16 pb = (__bf16)p;
        cs[nt] += (float)pb;            // sum the rounded value pass B will use
        slot[(size_t)(jl + r) * 128 + il] = pb;
      }
    }
  }
  __shared__ float lcs[4][64];
#pragma unroll
  for (int nt = 0; nt < 4; ++nt) {
    cs[nt] += __shfl_xor(cs[nt], 16);
    cs[nt] += __shfl_xor(cs[nt], 32);
  }
  if (quad == 0) {
#pragma unroll
    for (int nt = 0; nt < 4; ++nt) lcs[wave][nt * 16 + cl] = cs[nt];
  }
  __syncthreads();
  const int tid = threadIdx.x;
  if (tid < 128) {                      // block column c = tid
    const int w0 = (tid < 64) ? 0 : 1;  // waves {0,2} cols [0,64), {1,3} [64,128)
    const int lc = tid & 63;
    const float s = lcs[w0][lc] + lcs[w0 + 2][lc];
    partialD[((size_t)b * 16 + jt) * Tt + it * 128 + tid] = s;
  }
}

// ---------------------------------------------------------------------------
// dreduce: recipD[b][i] = 1 / sum_jt partialD[b][jt][i].  grid 64 x 256.
// ---------------------------------------------------------------------------
__global__ __launch_bounds__(256) void dreduce_kernel(
    const float* __restrict__ partialD, float* __restrict__ recipD)
{
  const int g = blockIdx.x * 256 + threadIdx.x;  // 0..16383
  const int b = g >> 11, i = g & (Tt - 1);
  float s = 0.f;
#pragma unroll
  for (int jt = 0; jt < 16; ++jt) s += partialD[((size_t)b * 16 + jt) * Tt + i];
  recipD[g] = 1.0f / s;
}

// ---------------------------------------------------------------------------
// vscale: vT[b][v][i] *= recipD[b][i]  (in place, bf16x8 per thread).
//   grid 2048 x 256.
// ---------------------------------------------------------------------------
__global__ __launch_bounds__(256) void vscale_kernel(
    bf16x8* __restrict__ vT8, const float* __restrict__ recipD)
{
  const int g = blockIdx.x * 256 + threadIdx.x;      // bf16x8 unit
  const size_t e0 = (size_t)g * 8;
  const int i = (int)(e0 & (Tt - 1));
  const int b = (int)(e0 >> 19);                     // 256*2048 elems per batch
  bf16x8 v = vT8[g];
  const f32x4 r0 = *(const f32x4*)(recipD + (size_t)b * Tt + i);
  const f32x4 r1 = *(const f32x4*)(recipD + (size_t)b * Tt + i + 4);
#pragma unroll
  for (int t = 0; t < 4; ++t) v[t] = (__bf16)((float)v[t] * r0[t]);
#pragma unroll
  for (int t = 0; t < 4; ++t) v[4 + t] = (__bf16)((float)v[4 + t] * r1[t]);
  vT8[g] = v;
}

// ---------------------------------------------------------------------------
// pvgemm: out[:, :, 256:512] = expS @ vT_scaled, triangular k-loop.
//   grid (32 jt2 reversed, 8 b), block 256 = 4 waves; all waves share the
//   64 j-rows, wave w owns v-cols [w*64, w*64+64). Per 128-k block: 16 A +
//   16 B direct 16B loads, 64 MFMAs. A from packed expS slots (row-major),
//   B from vT ([v][i], i contiguous).
// ---------------------------------------------------------------------------
__global__ __launch_bounds__(256) void pvgemm_kernel(
    const __bf16* __restrict__ expS, const __bf16* __restrict__ vT,
    float* __restrict__ out)
{
  const int b = blockIdx.y;
  const int jt2 = 31 - blockIdx.x;                   // longest first
  const int lane = threadIdx.x & 63, wave = threadIdx.x >> 6;
  const int cl = lane & 15, quad = lane >> 4;
  const int j0 = jt2 * 64;
  const int v0 = wave * 64;
  const int jt = jt2 >> 1;                           // 128-slot row
  const int jl0 = (jt2 & 1) * 64;
  const int nits = jt + 1;
  const size_t slotrow = (size_t)(b * NTRI + (jt * (jt + 1)) / 2);  // + it

  f32x4 acc[4][4];
#pragma unroll
  for (int mt = 0; mt < 4; ++mt)
#pragma unroll
    for (int nt = 0; nt < 4; ++nt) acc[mt][nt] = (f32x4){0.f, 0.f, 0.f, 0.f};

  const __bf16* vrow = vT + ((size_t)b * Vv + v0 + cl) * Tt + quad * 8;

  for (int it = 0; it < nits; ++it) {
    const __bf16* arow = expS + (slotrow + it) * (128 * 128)
                       + (size_t)(jl0 + cl) * 128 + quad * 8;
    const __bf16* brow = vrow + it * 128;
#pragma unroll
    for (int ks = 0; ks < 4; ++ks) {
      bf16x8 af[4], bfr[4];
#pragma unroll
      for (int mt = 0; mt < 4; ++mt) af[mt] = *(const bf16x8*)(arow + mt * 16 * 128 + ks * 32);
#pragma unroll
      for (int nt = 0; nt < 4; ++nt) bfr[nt] = *(const bf16x8*)(brow + (size_t)nt * 16 * Tt + ks * 32);
#pragma unroll
      for (int mt = 0; mt < 4; ++mt)
#pragma unroll
        for (int nt = 0; nt < 4; ++nt)
          acc[mt][nt] = __builtin_amdgcn_mfma_f32_16x16x32_bf16(af[mt], bfr[nt], acc[mt][nt], 0, 0, 0);
    }
  }

  float* orow = out + ((size_t)b * Tt + j0) * (size_t)(Cc + Vv) + Cc + v0;
#pragma unroll
  for (int mt = 0; mt < 4; ++mt)
#pragma unroll
    for (int nt = 0; nt < 4; ++nt)
#pragma unroll
      for (int r = 0; r < 4; ++r)
        orow[(size_t)(mt * 16 + quad * 4 + r) * (Cc + Vv) + nt * 16 + cl] = acc[mt][nt][r];
}

// ---------------------------------------------------------------------------
extern "C" void kernel_launch(void* const* d_in, const int* in_sizes, int n_in,
                              void* d_out, int out_size, void* d_ws, size_t ws_size,
                              hipStream_t stream) {
  const float* inp  = (const float*)d_in[0];
  const float* feat = (const float*)d_in[1];
  const float* Wq   = (const float*)d_in[2];
  const float* bq   = (const float*)d_in[3];
  const float* Wk   = (const float*)d_in[4];
  const float* bk   = (const float*)d_in[5];
  const float* Wv   = (const float*)d_in[6];
  const float* bv   = (const float*)d_in[7];
  float* out = (float*)d_out;

  // ws layout (~71 MB):
  //  inpB 8M | featB 8M | qb 4M | kb 4M | vT 8M | Wqt/Wkt/Wvt 320K |
  //  partialD 2M @33M | recipD 64K @35M | expS 34.8M @36M
  char* ws = (char*)d_ws;
  __bf16* inpB   = (__bf16*)(ws);
  __bf16* featB  = (__bf16*)(ws + (8u << 20));
  __bf16* qb     = (__bf16*)(ws + (16u << 20));
  __bf16* kb     = (__bf16*)(ws + (20u << 20));
  __bf16* vT     = (__bf16*)(ws + (24u << 20));
  __bf16* Wqt    = (__bf16*)(ws + (32u << 20));
  __bf16* Wkt    = (__bf16*)(ws + (32u << 20) + (128u << 10));
  __bf16* Wvt    = (__bf16*)(ws + (32u << 20) + (192u << 10));
  float*  partialD = (float*)(ws + (33u << 20));
  float*  recipD   = (float*)(ws + (35u << 20));
  __bf16* expS     = (__bf16*)(ws + (36u << 20));

  prep_kernel<<<dim3(BT * 64 / 256), 256, 0, stream>>>(
      (const float4*)inp, (const float4*)feat, (float4*)out,
      (bf16x4*)inpB, (bf16x4*)featB);
  wprep_kernel<<<dim3(640), 256, 0, stream>>>(Wq, Wk, Wv, Wqt, Wkt, Wvt);
  qkv_mfma_kernel<<<dim3(BT / 64, 4), 256, 0, stream>>>(
      inpB, featB, Wqt, Wkt, Wvt, bq, bk, bv, qb, kb, vT);
  sexp_kernel<<<dim3(NTRI, Bb), 256, 0, stream>>>(qb, kb, expS, partialD);
  dreduce_kernel<<<dim3(BT / 256), 256, 0, stream>>>(partialD, recipD);
  vscale_kernel<<<dim3(2048), 256, 0, stream>>>((bf16x8*)vT, recipD);
  pvgemm_kernel<<<dim3(Tt / 64, Bb), 256, 0, stream>>>(expS, vT, out);
}